// Round 15
// baseline (110.565 us; speedup 1.0000x reference)
//
#include <hip/hip_runtime.h>

// etp: out[n, coff(l3)+m3, u] = sum_p sum_{m1,m2} cg_p[m1,m2,m3] * Y[n, yoff(l1)+m1]
//                               * H[n, coff(l2)+m2, u] * W[n, p, u]
// N=16384 edges, 16 ch (l=0..3, dims 1,3,5,7), MUL=128.
//
// R14: f2 per thread (one wave/edge -> per-CU LDS b128 stream halves vs R13:
// 64 waves/CU x 158 x 12cyc = 50us) + R13's burst discipline done right:
// each l2-group loads hh[d2]+wg[npaths] together and ONE multi-operand asm
// pin forces all group loads to issue before any compute (R13's sequential
// pins let the allocator interleave; R11 had 27 at-use exposures at 41% occ).
// __launch_bounds__(256,6): 85-VGPR cap (R11 compiled to 52) -> 6 waves/EU.

#define BS 256
#define EPB 4     // edges per block (one wave each)
#define TPE 64    // threads per edge
#define YD 16
#define HD 2048
#define WD 2944
#define NROW 99   // sum of d3 over paths (B rows, padded to 8 floats)

typedef float f2 __attribute__((ext_vector_type(2)));
typedef float f4 __attribute__((ext_vector_type(4)));

// X(p, l1, l2, l3, cg_offset, row_offset) — build phase
#define FOR_PATHS(X) \
  X(0, 0,0,0,    0,  0) \
  X(1, 0,1,1,    1,  1) \
  X(2, 0,2,2,   10,  4) \
  X(3, 0,3,3,   35,  9) \
  X(4, 1,0,1,   84, 16) \
  X(5, 1,1,0,   93, 19) \
  X(6, 1,1,2,  102, 20) \
  X(7, 1,2,1,  147, 25) \
  X(8, 1,2,3,  192, 28) \
  X(9, 1,3,2,  297, 35) \
  X(10,2,0,2,  402, 40) \
  X(11,2,1,1,  427, 45) \
  X(12,2,1,3,  472, 48) \
  X(13,2,2,0,  577, 55) \
  X(14,2,2,2,  602, 56) \
  X(15,2,3,1,  727, 61) \
  X(16,2,3,3,  832, 64) \
  X(17,3,0,3, 1077, 71) \
  X(18,3,1,2, 1126, 78) \
  X(19,3,2,1, 1231, 83) \
  X(20,3,2,3, 1336, 86) \
  X(21,3,3,0, 1581, 93) \
  X(22,3,3,2, 1630, 94)

__host__ __device__ constexpr int coff(int l) {
  return l == 0 ? 0 : (l == 1 ? 1 : (l == 2 ? 4 : 9));
}

__global__ __launch_bounds__(BS, 6) void etp_kernel(
    const float* __restrict__ Y, const float* __restrict__ H,
    const float* __restrict__ W, const float* __restrict__ CG,
    float* __restrict__ O) {
  const int g = threadIdx.x >> 6;   // edge within block
  const int l = threadIdx.x & 63;   // lane; owns u = 2l, 2l+1
  const size_t n = (size_t)blockIdx.x * EPB + g;

  __shared__ __align__(16) float Bsm[EPB][NROW * 8];  // 12672 B
  __shared__ float ysm[EPB][YD];

  { const int t = threadIdx.x;
    if (t < EPB * YD) {
      const int e = t >> 4, c = t & 15;
      ysm[e][c] = Y[(size_t)(blockIdx.x * EPB + e) * YD + c];
    } }
  __syncthreads();

  // Phase 1: B_p[m3][m2] = sum_a cg_p[a,m2,m3] * y[coff(l1)+a]; d2*d3<=49<64.
#define BUILD(P, L1, L2, L3, CGO, RO) { \
    constexpr int d1 = 2*(L1)+1, d2 = 2*(L2)+1, d3 = 2*(L3)+1; \
    if (l < d2 * d3) { \
      const int m3 = l / d2, m2 = l - m3 * d2; \
      float s = 0.f; \
      _Pragma("unroll") \
      for (int a = 0; a < d1; ++a) \
        s += CG[(CGO) + (a * d2 + m2) * d3 + m3] * ysm[g][coff(L1) + a]; \
      Bsm[g][((RO) + m3) * 8 + m2] = s; \
    } }
  FOR_PATHS(BUILD)
#undef BUILD
  __syncthreads();

  // Phase 2: f2 contraction; per-l2-group atomic bursts of hh+wg.
  const f2* __restrict__ Hp = (const f2*)(H + n * HD);
  const f2* __restrict__ Wp = (const f2*)(W + n * WD);
  f2* __restrict__ Op = (f2*)(O + n * HD);

  f2 acc[YD];
#pragma unroll
  for (int c = 0; c < YD; ++c) acc[c] = (f2)0.f;

#define DOP(WI, L2V, L3V, RO) { \
    constexpr int d2 = 2*(L2V)+1, d3 = 2*(L3V)+1; \
    const f2 wv = wg[WI]; \
    _Pragma("unroll") \
    for (int m3 = 0; m3 < d3; ++m3) { \
      const f4* row = (const f4*)&Bsm[g][((RO) + m3) * 8]; \
      float br[8]; \
      *(f4*)&br[0] = row[0]; \
      if (d2 > 4) *(f4*)&br[4] = row[1]; \
      f2 s = (f2)0.f; \
      _Pragma("unroll") \
      for (int m2 = 0; m2 < d2; ++m2) s += br[m2] * hh[m2]; \
      acc[coff(L3V) + m3] += s * wv; \
    } }

  { // l2=0: paths 0,4,10,17
    f2 hh[1], wg[4];
    hh[0] = Hp[0 * TPE + l];
    wg[0] = Wp[0 * TPE + l];  wg[1] = Wp[4 * TPE + l];
    wg[2] = Wp[10 * TPE + l]; wg[3] = Wp[17 * TPE + l];
    asm volatile("" : "+v"(hh[0]), "+v"(wg[0]), "+v"(wg[1]), "+v"(wg[2]),
                      "+v"(wg[3]));
    DOP(0, 0, 0, 0)  DOP(1, 0, 1, 16)  DOP(2, 0, 2, 40)  DOP(3, 0, 3, 71)
  }
  { // l2=1: paths 1,5,6,11,12,18
    f2 hh[3], wg[6];
#pragma unroll
    for (int m = 0; m < 3; ++m) hh[m] = Hp[(1 + m) * TPE + l];
    wg[0] = Wp[1 * TPE + l];  wg[1] = Wp[5 * TPE + l];
    wg[2] = Wp[6 * TPE + l];  wg[3] = Wp[11 * TPE + l];
    wg[4] = Wp[12 * TPE + l]; wg[5] = Wp[18 * TPE + l];
    asm volatile("" : "+v"(hh[0]), "+v"(hh[1]), "+v"(hh[2]),
                      "+v"(wg[0]), "+v"(wg[1]), "+v"(wg[2]),
                      "+v"(wg[3]), "+v"(wg[4]), "+v"(wg[5]));
    DOP(0, 1, 1, 1)   DOP(1, 1, 0, 19)  DOP(2, 1, 2, 20)
    DOP(3, 1, 1, 45)  DOP(4, 1, 3, 48)  DOP(5, 1, 2, 78)
  }
  { // l2=2: paths 2,7,8,13,14,19,20
    f2 hh[5], wg[7];
#pragma unroll
    for (int m = 0; m < 5; ++m) hh[m] = Hp[(4 + m) * TPE + l];
    wg[0] = Wp[2 * TPE + l];  wg[1] = Wp[7 * TPE + l];
    wg[2] = Wp[8 * TPE + l];  wg[3] = Wp[13 * TPE + l];
    wg[4] = Wp[14 * TPE + l]; wg[5] = Wp[19 * TPE + l];
    wg[6] = Wp[20 * TPE + l];
    asm volatile("" : "+v"(hh[0]), "+v"(hh[1]), "+v"(hh[2]), "+v"(hh[3]),
                      "+v"(hh[4]),
                      "+v"(wg[0]), "+v"(wg[1]), "+v"(wg[2]), "+v"(wg[3]),
                      "+v"(wg[4]), "+v"(wg[5]), "+v"(wg[6]));
    DOP(0, 2, 2, 4)   DOP(1, 2, 1, 25)  DOP(2, 2, 3, 28)
    DOP(3, 2, 0, 55)  DOP(4, 2, 2, 56)  DOP(5, 2, 1, 83)  DOP(6, 2, 3, 86)
  }
  { // l2=3: paths 3,9,15,16,21,22
    f2 hh[7], wg[6];
#pragma unroll
    for (int m = 0; m < 7; ++m) hh[m] = Hp[(9 + m) * TPE + l];
    wg[0] = Wp[3 * TPE + l];  wg[1] = Wp[9 * TPE + l];
    wg[2] = Wp[15 * TPE + l]; wg[3] = Wp[16 * TPE + l];
    wg[4] = Wp[21 * TPE + l]; wg[5] = Wp[22 * TPE + l];
    asm volatile("" : "+v"(hh[0]), "+v"(hh[1]), "+v"(hh[2]), "+v"(hh[3]),
                      "+v"(hh[4]), "+v"(hh[5]), "+v"(hh[6]),
                      "+v"(wg[0]), "+v"(wg[1]), "+v"(wg[2]), "+v"(wg[3]),
                      "+v"(wg[4]), "+v"(wg[5]));
    DOP(0, 3, 3, 9)   DOP(1, 3, 2, 35)  DOP(2, 3, 1, 61)
    DOP(3, 3, 3, 64)  DOP(4, 3, 0, 93)  DOP(5, 3, 2, 94)
  }
#undef DOP

#pragma unroll
  for (int c = 0; c < YD; ++c)
    __builtin_nontemporal_store(acc[c], &Op[c * TPE + l]);
}

extern "C" void kernel_launch(void* const* d_in, const int* in_sizes, int n_in,
                              void* d_out, int out_size, void* d_ws, size_t ws_size,
                              hipStream_t stream) {
  const float* Y  = (const float*)d_in[0];
  const float* H  = (const float*)d_in[1];
  const float* W  = (const float*)d_in[2];
  const float* CG = (const float*)d_in[3];
  float* O = (float*)d_out;

  const int n_edges = in_sizes[0] / YD;        // 16384
  etp_kernel<<<n_edges / EPB, BS, 0, stream>>>(Y, H, W, CG, O);
}

// Round 16
// 101.604 us; speedup vs baseline: 1.0882x; 1.0882x over previous
//
#include <hip/hip_runtime.h>

// etp: out[n, coff(l3)+m3, u] = sum_p sum_{m1,m2} cg_p[m1,m2,m3] * Y[n, yoff(l1)+m1]
//                               * H[n, coff(l2)+m2, u] * W[n, p, u]
// N=16384 edges, 16 ch (l=0..3, dims 1,3,5,7), MUL=128.
//
// R15: kill the B-broadcast LDS stream (R13's 95us == 158 ds_read_b128/wave
// x 32768 waves at ~11.6cyc on the per-CU LDS pipe). Each wave builds B in
// ITS OWN REGISTERS (lane m3*d2+m2 holds B_p[m3][m2]; CG gathered from LDS,
// 99 conflict-free scalar reads; y broadcast via readlane) and consumes via
// v_readlane -> SGPR -> v_fmac(acc, sB, vH). Phase-2 LDS: 158 b128 -> 0.
// Proven elements kept: scalar threads (no f2/f4 allocator traps - R10/R14),
// l2-grouped short h/w live ranges, per-group burst+pin (R13), nontemporal
// stores, launch_bounds(256,7) = 73-VGPR cap for the ~55-reg live set.

#define BS 256
#define EPB 2     // edges per block
#define TPE 128   // threads per edge
#define YD 16
#define HD 2048
#define WD 2944
#define CGTOT 1875

__host__ __device__ constexpr int coff(int l) {
  return l == 0 ? 0 : (l == 1 ? 1 : (l == 2 ? 4 : 9));
}

__device__ __forceinline__ float rl(float v, int lane) {
  return __int_as_float(__builtin_amdgcn_readlane(__float_as_int(v), lane));
}

__global__ __launch_bounds__(BS, 7) void etp_kernel(
    const float* __restrict__ Yg, const float* __restrict__ Hg,
    const float* __restrict__ Wg, const float* __restrict__ CGg,
    float* __restrict__ Og) {
  __shared__ float cgs[CGTOT];  // 7.5 KB
  for (int i = threadIdx.x; i < CGTOT; i += BS) cgs[i] = CGg[i];

  const int g = threadIdx.x >> 7;    // edge within block
  const int u = threadIdx.x & 127;   // u index
  const int l = threadIdx.x & 63;    // lane within wave
  const size_t n = (size_t)blockIdx.x * EPB + g;

  __syncthreads();  // cgs ready (only barrier)

  // y -> wave-uniform yy[16] (SGPRs) via readlane broadcast.
  float yv = Yg[n * YD + (l & 15)];
  float yy[YD];
#pragma unroll
  for (int c = 0; c < YD; ++c) yy[c] = rl(yv, c);

  const float* __restrict__ Hn = Hg + n * HD + u;
  const float* __restrict__ Wn = Wg + n * WD + u;
  float* __restrict__ On = Og + n * HD + u;

  float acc[YD];
#pragma unroll
  for (int c = 0; c < YD; ++c) acc[c] = 0.f;

  // Build path P's B into per-wave register vB: lane m3*D2+m2 holds
  // B_P[m3][m2] = sum_a cg[a,m2,m3] * y[coff(L1)+a]. CG gather from LDS is
  // conflict-free (<=49 consecutive words, <=2 lanes/bank).
#define BLD(vB, L1, D2, D3, CGO) \
  if (l < (D2) * (D3)) { \
    float s_ = 0.f; \
    _Pragma("unroll") \
    for (int a = 0; a < 2 * (L1) + 1; ++a) \
      s_ += cgs[(CGO) + (a * (D2) + m2g) * (D3) + m3g] * yy[coff(L1) + a]; \
    vB = s_; \
  }

  // Consume: B via readlane (imm lane after unroll) -> SGPR operand of FMA.
#define CONS(vB, D2, D3, L3, WV) { \
    _Pragma("unroll") \
    for (int m3 = 0; m3 < (D3); ++m3) { \
      float s_ = 0.f; \
      _Pragma("unroll") \
      for (int m2 = 0; m2 < (D2); ++m2) \
        s_ += rl(vB, m3 * (D2) + m2) * hh[m2]; \
      acc[coff(L3) + m3] += s_ * (WV); \
    } }

  { // l2=0 (d2=1): p0(l1=0,l3=0) p4(1,1) p10(2,2) p17(3,3)
    float hh[1], wg[4];
    hh[0] = Hn[0 * TPE];
    wg[0] = Wn[0 * TPE];  wg[1] = Wn[4 * TPE];
    wg[2] = Wn[10 * TPE]; wg[3] = Wn[17 * TPE];
    asm volatile("" : "+v"(hh[0]), "+v"(wg[0]), "+v"(wg[1]), "+v"(wg[2]),
                      "+v"(wg[3]));
    const int m3g = l, m2g = 0;
    float b0 = 0.f, b4 = 0.f, b10 = 0.f, b17 = 0.f;
    BLD(b0, 0, 1, 1, 0)      BLD(b4, 1, 1, 3, 84)
    BLD(b10, 2, 1, 5, 402)   BLD(b17, 3, 1, 7, 1077)
    CONS(b0, 1, 1, 0, wg[0])   CONS(b4, 1, 3, 1, wg[1])
    CONS(b10, 1, 5, 2, wg[2])  CONS(b17, 1, 7, 3, wg[3])
  }
  { // l2=1 (d2=3): p1(0,1) p5(1,0) p6(1,2) p11(2,1) p12(2,3) p18(3,2)
    float hh[3], wg[6];
#pragma unroll
    for (int m = 0; m < 3; ++m) hh[m] = Hn[(1 + m) * TPE];
    wg[0] = Wn[1 * TPE];  wg[1] = Wn[5 * TPE];  wg[2] = Wn[6 * TPE];
    wg[3] = Wn[11 * TPE]; wg[4] = Wn[12 * TPE]; wg[5] = Wn[18 * TPE];
    asm volatile("" : "+v"(hh[0]), "+v"(hh[1]), "+v"(hh[2]),
                      "+v"(wg[0]), "+v"(wg[1]), "+v"(wg[2]),
                      "+v"(wg[3]), "+v"(wg[4]), "+v"(wg[5]));
    const int m3g = l / 3, m2g = l - m3g * 3;
    float b1 = 0.f, b5 = 0.f, b6 = 0.f, b11 = 0.f, b12 = 0.f, b18 = 0.f;
    BLD(b1, 0, 3, 3, 1)      BLD(b5, 1, 3, 1, 93)    BLD(b6, 1, 3, 5, 102)
    BLD(b11, 2, 3, 3, 427)   BLD(b12, 2, 3, 7, 472)  BLD(b18, 3, 3, 5, 1126)
    CONS(b1, 3, 3, 1, wg[0])   CONS(b5, 3, 1, 0, wg[1])   CONS(b6, 3, 5, 2, wg[2])
    CONS(b11, 3, 3, 1, wg[3])  CONS(b12, 3, 7, 3, wg[4])  CONS(b18, 3, 5, 2, wg[5])
  }
  { // l2=2 (d2=5): p2(0,2) p7(1,1) p8(1,3) p13(2,0) p14(2,2) p19(3,1) p20(3,3)
    float hh[5], wg[7];
#pragma unroll
    for (int m = 0; m < 5; ++m) hh[m] = Hn[(4 + m) * TPE];
    wg[0] = Wn[2 * TPE];  wg[1] = Wn[7 * TPE];  wg[2] = Wn[8 * TPE];
    wg[3] = Wn[13 * TPE]; wg[4] = Wn[14 * TPE]; wg[5] = Wn[19 * TPE];
    wg[6] = Wn[20 * TPE];
    asm volatile("" : "+v"(hh[0]), "+v"(hh[1]), "+v"(hh[2]), "+v"(hh[3]),
                      "+v"(hh[4]),
                      "+v"(wg[0]), "+v"(wg[1]), "+v"(wg[2]), "+v"(wg[3]),
                      "+v"(wg[4]), "+v"(wg[5]), "+v"(wg[6]));
    const int m3g = l / 5, m2g = l - m3g * 5;
    float b2 = 0.f, b7 = 0.f, b8 = 0.f, b13 = 0.f, b14 = 0.f, b19 = 0.f,
          b20 = 0.f;
    BLD(b2, 0, 5, 5, 10)     BLD(b7, 1, 5, 3, 147)   BLD(b8, 1, 5, 7, 192)
    BLD(b13, 2, 5, 1, 577)   BLD(b14, 2, 5, 5, 602)  BLD(b19, 3, 5, 3, 1231)
    BLD(b20, 3, 5, 7, 1336)
    CONS(b2, 5, 5, 2, wg[0])   CONS(b7, 5, 3, 1, wg[1])   CONS(b8, 5, 7, 3, wg[2])
    CONS(b13, 5, 1, 0, wg[3])  CONS(b14, 5, 5, 2, wg[4])  CONS(b19, 5, 3, 1, wg[5])
    CONS(b20, 5, 7, 3, wg[6])
  }
  { // l2=3 (d2=7): p3(0,3) p9(1,2) p15(2,1) p16(2,3) p21(3,0) p22(3,2)
    float hh[7], wg[6];
#pragma unroll
    for (int m = 0; m < 7; ++m) hh[m] = Hn[(9 + m) * TPE];
    wg[0] = Wn[3 * TPE];  wg[1] = Wn[9 * TPE];  wg[2] = Wn[15 * TPE];
    wg[3] = Wn[16 * TPE]; wg[4] = Wn[21 * TPE]; wg[5] = Wn[22 * TPE];
    asm volatile("" : "+v"(hh[0]), "+v"(hh[1]), "+v"(hh[2]), "+v"(hh[3]),
                      "+v"(hh[4]), "+v"(hh[5]), "+v"(hh[6]),
                      "+v"(wg[0]), "+v"(wg[1]), "+v"(wg[2]), "+v"(wg[3]),
                      "+v"(wg[4]), "+v"(wg[5]));
    const int m3g = l / 7, m2g = l - m3g * 7;
    float b3 = 0.f, b9 = 0.f, b15 = 0.f, b16 = 0.f, b21 = 0.f, b22 = 0.f;
    BLD(b3, 0, 7, 7, 35)     BLD(b9, 1, 7, 5, 297)   BLD(b15, 2, 7, 3, 727)
    BLD(b16, 2, 7, 7, 832)   BLD(b21, 3, 7, 1, 1581) BLD(b22, 3, 7, 5, 1630)
    CONS(b3, 7, 7, 3, wg[0])   CONS(b9, 7, 5, 2, wg[1])   CONS(b15, 7, 3, 1, wg[2])
    CONS(b16, 7, 7, 3, wg[3])  CONS(b21, 7, 1, 0, wg[4])  CONS(b22, 7, 5, 2, wg[5])
  }
#undef BLD
#undef CONS

#pragma unroll
  for (int c = 0; c < YD; ++c)
    __builtin_nontemporal_store(acc[c], &On[c * TPE]);
}

extern "C" void kernel_launch(void* const* d_in, const int* in_sizes, int n_in,
                              void* d_out, int out_size, void* d_ws, size_t ws_size,
                              hipStream_t stream) {
  const float* Y  = (const float*)d_in[0];
  const float* H  = (const float*)d_in[1];
  const float* W  = (const float*)d_in[2];
  const float* CG = (const float*)d_in[3];
  float* O = (float*)d_out;

  const int n_edges = in_sizes[0] / YD;        // 16384
  etp_kernel<<<n_edges / EPB, BS, 0, stream>>>(Y, H, W, CG, O);
}